// Round 1
// baseline (251.574 us; speedup 1.0000x reference)
//
#include <hip/hip_runtime.h>

// LoG: GaussianBlur(3x3, sigma=1, BORDER_REFLECT_101) -> Laplacian(ksize=9) -> +1 -> clip[0,255]
// x: [32,512,512,3] float32 NHWC. out: same.
//
// Laplacian 9x9 kernel = outer(S9,D9)+outer(D9,S9) -> two separable passes:
//   t1 = vert(S9, blur); t2 = vert(D9, blur); out = horz(D9,t1) + horz(S9,t2) + 1
// Reflect-101 is applied at EACH stage in the reference, so boundary blur values
// are blur[reflect(g)] where blur itself read x[reflect(.)] -- handled exactly via
// per-block double-reflect LUTs (rows in stage 2, columns folded into stage 1).

#define TH 32
#define TW 32
#define FW (TW*3)        // 96 output floats per tile row
#define BW (TW+8)        // 40 blur pixels wide (±4 halo)
#define BF (BW*3)        // 120 floats
#define BH (TH+8)        // 40 blur rows
#define XHMAX (TH+10)    // 42 max staged x rows
#define HIMG 512
#define WIMG 512
#define ROWF (WIMG*3)    // 1536 floats per image row

// LDS float layout:
//   blur  : [0, 4800)                BH*BF
//   hblur : [4800, 9840)             XHMAX*BF   (dead after stage 2)
//   t1    : [4800, 8640)             TH*BF      (aliases hblur)
//   t2    : [8640, 12480)            TH*BF
#define SM_TOTAL 12480

__device__ __forceinline__ int reflect101(int i, int n) {
    i = (i < 0) ? -i : i;
    return (i >= n) ? (2 * n - 2 - i) : i;
}

__device__ __forceinline__ float4 fma4(float s, const float4& a, const float4& b) {
    return make_float4(fmaf(s, a.x, b.x), fmaf(s, a.y, b.y),
                       fmaf(s, a.z, b.z), fmaf(s, a.w, b.w));
}

__global__ __launch_bounds__(256, 3)
void log_fused(const float* __restrict__ x, float* __restrict__ out) {
    __shared__ __align__(16) float smem[SM_TOTAL];
    __shared__ int brow[BH][3];
    float* const blur  = smem;
    float* const hblur = smem + 4800;
    float* const t1    = smem + 4800;
    float* const t2    = smem + 8640;

    const int tid  = threadIdx.x;
    const int col0 = blockIdx.x * TW;
    const int row0 = blockIdx.y * TH;
    const int n    = blockIdx.z;

    const int R0    = max(0, row0 - 5);
    const int R1    = min(HIMG - 1, row0 + TH + 4);
    const int nrows = R1 - R0 + 1;   // <= 42; all double-reflected rows land in [R0,R1]

    // Row LUT for stage 2: blur tile row lr corresponds to global blur row
    // g = row0-4+lr; the Laplacian pad reads blur[reflect(g)] = gr, and that blur
    // value was computed from hblur rows reflect(gr-1), gr, reflect(gr+1).
    if (tid < BH) {
        int gr = reflect101(row0 - 4 + tid, HIMG);
        brow[tid][0] = reflect101(gr - 1, HIMG) - R0;
        brow[tid][1] = gr - R0;
        brow[tid][2] = reflect101(gr + 1, HIMG) - R0;
    }

    const float G0 = 0.2740686190f, G1 = 0.4518627620f;  // normalized exp(-{1,0,1}/2)

    // ---- stage 1: horizontal 3-tap Gaussian, global -> hblur ----
    // column-stationary threads: per-thread reflect indices computed once.
    if (tid < 240) {
        const int lc  = tid % BF;
        const int rg  = tid / BF;           // 0 or 1
        const int lcp = lc / 3;
        const int ch  = lc - 3 * lcp;
        const int gc  = reflect101(col0 - 4 + lcp, WIMG);   // double-reflect: tile col -> real col
        const int xm  = reflect101(gc - 1, WIMG) * 3 + ch;
        const int x0  = gc * 3 + ch;
        const int xp  = reflect101(gc + 1, WIMG) * 3 + ch;
        const float* xr = x + ((size_t)n * HIMG + (size_t)(R0 + rg)) * ROWF;
        for (int r = rg; r < nrows; r += 2, xr += 2 * ROWF) {
            hblur[r * BF + lc] = G0 * (xr[xm] + xr[xp]) + G1 * xr[x0];
        }
    }
    __syncthreads();

    // ---- stage 2: vertical 3-tap Gaussian with reflect LUT, hblur -> blur ----
    for (int e = tid; e < (BH * BF) / 4; e += 256) {
        int lr = e / (BF / 4);
        int qc = e - lr * (BF / 4);
        int lc = qc * 4;
        const float4 a = *(const float4*)&hblur[brow[lr][0] * BF + lc];
        const float4 b = *(const float4*)&hblur[brow[lr][1] * BF + lc];
        const float4 c = *(const float4*)&hblur[brow[lr][2] * BF + lc];
        float4 r;
        r.x = G0 * (a.x + c.x) + G1 * b.x;
        r.y = G0 * (a.y + c.y) + G1 * b.y;
        r.z = G0 * (a.z + c.z) + G1 * b.z;
        r.w = G0 * (a.w + c.w) + G1 * b.w;
        *(float4*)&blur[lr * BF + lc] = r;
    }
    __syncthreads();   // hblur dead beyond this point; t1/t2 may overwrite it

    const float S9[9] = {1.f, 8.f, 28.f, 56.f, 70.f, 56.f, 28.f, 8.f, 1.f};
    const float D9[9] = {1.f, 4.f, 4.f, -4.f, -10.f, -4.f, 4.f, 4.f, 1.f};

    // ---- stage 3a: vertical 9-tap S and D, blur -> t1,t2 (2-row register block) ----
    for (int g = tid; g < (TH / 2) * (BF / 4); g += 256) {   // 480 groups
        int rg  = g / (BF / 4);
        int qc  = g - rg * (BF / 4);
        int lr0 = rg * 2;
        int lc  = qc * 4;
        float4 w[10];
        #pragma unroll
        for (int k = 0; k < 10; ++k)
            w[k] = *(const float4*)&blur[(lr0 + k) * BF + lc];
        float4 a1r0 = make_float4(0.f, 0.f, 0.f, 0.f), a2r0 = a1r0;
        float4 a1r1 = a1r0, a2r1 = a1r0;
        #pragma unroll
        for (int k = 0; k < 9; ++k) {
            a1r0 = fma4(S9[k], w[k],     a1r0);
            a2r0 = fma4(D9[k], w[k],     a2r0);
            a1r1 = fma4(S9[k], w[k + 1], a1r1);
            a2r1 = fma4(D9[k], w[k + 1], a2r1);
        }
        *(float4*)&t1[(lr0    ) * BF + lc] = a1r0;
        *(float4*)&t1[(lr0 + 1) * BF + lc] = a1r1;
        *(float4*)&t2[(lr0    ) * BF + lc] = a2r0;
        *(float4*)&t2[(lr0 + 1) * BF + lc] = a2r1;
    }
    __syncthreads();

    // ---- stage 3b: horizontal 9-tap D(t1)+S(t2), +1, clip, store ----
    float* const outn = out + (size_t)n * HIMG * ROWF;
    for (int g = tid; g < TH * (FW / 8); g += 256) {   // 384 groups of 8 outputs
        int lr = g / (FW / 8);
        int qp = g - lr * (FW / 8);
        int lc = qp * 8;
        float w1[32], w2[32];
        #pragma unroll
        for (int q = 0; q < 8; ++q) {
            float4 v = *(const float4*)&t1[lr * BF + lc + 4 * q];
            w1[4*q+0] = v.x; w1[4*q+1] = v.y; w1[4*q+2] = v.z; w1[4*q+3] = v.w;
            float4 u = *(const float4*)&t2[lr * BF + lc + 4 * q];
            w2[4*q+0] = u.x; w2[4*q+1] = u.y; w2[4*q+2] = u.z; w2[4*q+3] = u.w;
        }
        float o[8];
        #pragma unroll
        for (int j = 0; j < 8; ++j) {
            float a = 1.0f;   // delta = 1
            #pragma unroll
            for (int k = 0; k < 9; ++k) {
                a = fmaf(D9[k], w1[j + 3 * k], a);   // horizontal taps at +3k floats (same channel)
                a = fmaf(S9[k], w2[j + 3 * k], a);
            }
            o[j] = fminf(fmaxf(a, 0.0f), 255.0f);
        }
        float* op = outn + (size_t)(row0 + lr) * ROWF + (size_t)(col0 * 3 + lc);
        *(float4*)&op[0] = make_float4(o[0], o[1], o[2], o[3]);
        *(float4*)&op[4] = make_float4(o[4], o[5], o[6], o[7]);
    }
}

extern "C" void kernel_launch(void* const* d_in, const int* in_sizes, int n_in,
                              void* d_out, int out_size, void* d_ws, size_t ws_size,
                              hipStream_t stream) {
    const float* x = (const float*)d_in[0];
    float* outp = (float*)d_out;
    const int nimg = in_sizes[0] / (HIMG * WIMG * 3);
    dim3 grid(WIMG / TW, HIMG / TH, nimg);
    log_fused<<<grid, dim3(256, 1, 1), 0, stream>>>(x, outp);
}